// Round 2
// baseline (2938.772 us; speedup 1.0000x reference)
//
#include <hip/hip_runtime.h>
#include <math.h>

#define BB 512
#define SS 16
#define HH 501
#define CC 7
#define OFF_ENC (BB*SS*SS)   // dep-graph output floats, then node-encoding

// ---------------- prep: zT[k][b] = z[b][k]; cls[s][b] = argmax_c xenc ----------------
__global__ __launch_bounds__(256) void k_prep(
    const float* __restrict__ z, const float* __restrict__ xenc,
    float* __restrict__ zT, int* __restrict__ cls)
{
    if ((int)blockIdx.x < 256) {
        __shared__ float t[32][33];
        const int bt = blockIdx.x >> 4, kt = blockIdx.x & 15;
        const int b0 = bt * 32, k0 = kt * 32;
        const int tx = threadIdx.x & 31, ty = threadIdx.x >> 5;  // ty in [0,8)
#pragma unroll
        for (int i = 0; i < 4; ++i) {
            int row = ty + i * 8;
            if (k0 + tx < HH) t[row][tx] = z[(b0 + row) * HH + k0 + tx];
        }
        __syncthreads();
#pragma unroll
        for (int i = 0; i < 4; ++i) {
            int row = ty + i * 8;
            if (k0 + row < HH) zT[(k0 + row) * BB + b0 + tx] = t[tx][row];
        }
    } else {
        int e = ((int)blockIdx.x - 256) * 256 + threadIdx.x;  // [0, 8192)
        int s = e >> 9, b = e & 511;
        const float* xp = xenc + (b * SS + s) * CC;
        int c = 0;
#pragma unroll
        for (int q = 0; q < CC; ++q) if (xp[q] > 0.5f) c = q;
        cls[s * BB + b] = c;
    }
}

// ---------------- g0T[r][b] = (z @ Wlin1^T + b)^T ----------------
__global__ __launch_bounds__(256) void k_g0(
    const float* __restrict__ zT, const float* __restrict__ W,
    const float* __restrict__ bias, float* __restrict__ g0T)
{
    const int lane = threadIdx.x & 63;
    const int wv = __builtin_amdgcn_readfirstlane(threadIdx.x >> 6);
    const int bb = blockIdx.x & 7;
    const int rb = ((int)blockIdx.x >> 3) * 16 + wv * 4;
    const int b = bb * 64 + lane;
    int ri[4];
#pragma unroll
    for (int i = 0; i < 4; ++i) ri[i] = min(rb + i, HH - 1);
    const float* w[4];
#pragma unroll
    for (int i = 0; i < 4; ++i) w[i] = W + ri[i] * HH;
    float acc[4] = {};
    const float* ap = zT + b;
#pragma unroll 4
    for (int k = 0; k < HH; ++k) {
        float av = ap[k * BB];
#pragma unroll
        for (int i = 0; i < 4; ++i) acc[i] = fmaf(w[i][k], av, acc[i]);
    }
#pragma unroll
    for (int i = 0; i < 4; ++i)
        if (rb + i < HH) g0T[ri[i] * BB + b] = acc[i] + bias[ri[i]];
}

// ---------------- per-step GRU: hT[r][b] = GRUCell(x_idx, hin)^T ----------------
// gh = hin @ Whh^T (3 groups, scalar weight streams); gi = Wih[.,cls] gather
__global__ __launch_bounds__(256) void k_gru2(
    const float* __restrict__ AT,   // hin^T [H][B] (g0T at idx 0)
    const float* __restrict__ Whh, const float* __restrict__ bhh,
    const float* __restrict__ Wih, const float* __restrict__ bih,
    const int* __restrict__ cls, int idx,
    float* __restrict__ hT)
{
    const int lane = threadIdx.x & 63;
    const int wv = __builtin_amdgcn_readfirstlane(threadIdx.x >> 6);
    const int bb = blockIdx.x & 7;
    const int rb = ((int)blockIdx.x >> 3) * 16 + wv * 4;
    const int b = bb * 64 + lane;
    int ri[4];
#pragma unroll
    for (int i = 0; i < 4; ++i) ri[i] = min(rb + i, HH - 1);
    const float* w[12];
#pragma unroll
    for (int g = 0; g < 3; ++g)
#pragma unroll
        for (int i = 0; i < 4; ++i) w[g * 4 + i] = Whh + (g * HH + ri[i]) * HH;
    float acc[12] = {};
    const float* ap = AT + b;
#pragma unroll 4
    for (int k = 0; k < HH; ++k) {
        float av = ap[k * BB];
#pragma unroll
        for (int j = 0; j < 12; ++j) acc[j] = fmaf(w[j][k], av, acc[j]);
    }
    const int c = cls[idx * BB + b];
#pragma unroll
    for (int i = 0; i < 4; ++i) {
        int r = ri[i];
        float gh0 = acc[0 + i] + bhh[r];
        float gh1 = acc[4 + i] + bhh[HH + r];
        float gh2 = acc[8 + i] + bhh[2 * HH + r];
        float gi0 = Wih[(0 * HH + r) * CC + c] + bih[r];
        float gi1 = Wih[(1 * HH + r) * CC + c] + bih[HH + r];
        float gi2 = Wih[(2 * HH + r) * CC + c] + bih[2 * HH + r];
        float rg = 1.f / (1.f + expf(-(gi0 + gh0)));
        float ug = 1.f / (1.f + expf(-(gi1 + gh1)));
        float ng = tanhf(gi2 + rg * gh2);
        float hv = (1.f - ug) * ng + ug * AT[r * BB + b];  // hidden input = hin
        if (rb + i < HH) hT[r * BB + b] = hv;
    }
}

// ---------------- post: hinT for next step (ngemm blocks) + dots/outputs ----------------
__global__ __launch_bounds__(256) void k_post2(
    const float* __restrict__ hT,
    const float* __restrict__ Wgate, const float* __restrict__ bgate,
    const float* __restrict__ Wmap,  const float* __restrict__ bmap,
    const float* __restrict__ dep,
    const float* __restrict__ Wedge, const float* __restrict__ bedge,
    const float* __restrict__ Wvert, const float* __restrict__ bvert,
    int idx, int ngemm,
    float* __restrict__ hinT, float* __restrict__ Alist,
    float* __restrict__ Elist, float* __restrict__ out)
{
    const int lane = threadIdx.x & 63;
    const int wv = __builtin_amdgcn_readfirstlane(threadIdx.x >> 6);
    if ((int)blockIdx.x < ngemm) {
        const int bb = blockIdx.x & 7;
        const int rb = ((int)blockIdx.x >> 3) * 16 + wv * 4;
        const int b = bb * 64 + lane;
        int ri[4];
#pragma unroll
        for (int i = 0; i < 4; ++i) ri[i] = min(rb + i, HH - 1);
        const float* wg[4]; const float* wm[4];
#pragma unroll
        for (int i = 0; i < 4; ++i) { wg[i] = Wgate + ri[i] * HH; wm[i] = Wmap + ri[i] * HH; }
        float acc[8] = {};
        const float* ap = hT + b;
#pragma unroll 4
        for (int k = 0; k < HH; ++k) {
            float av = ap[k * BB];
#pragma unroll
            for (int i = 0; i < 4; ++i) {
                acc[i]     = fmaf(wg[i][k], av, acc[i]);
                acc[4 + i] = fmaf(wm[i][k], av, acc[4 + i]);
            }
        }
        const float d = dep[b * (SS * SS) + (idx + 1) * SS + idx];
#pragma unroll
        for (int i = 0; i < 4; ++i) {
            int r = ri[i];
            float bg = bgate[r], bm = bmap[r];
            float yg = acc[i] + bg, ym = acc[4 + i] + bm;
            float f  = (1.f / (1.f + expf(-yg))) * ym;
            float c0 = (1.f / (1.f + expf(-bg))) * bm;
            float hin = (d != 0.f) ? (f + 15.f * c0) : (16.f * c0);
            if (rb + i < HH) hinT[r * BB + b] = hin;
        }
    } else {
        const int b = ((int)blockIdx.x - ngemm) * 256 + threadIdx.x;  // [0,512)
        float p[9] = {};
        const float* ap = hT + b;
#pragma unroll 4
        for (int k = 0; k < HH; ++k) {
            float av = ap[k * BB];
            p[0] = fmaf(Wedge[k], av, p[0]);
            p[1] = fmaf(Wedge[HH + k], av, p[1]);
#pragma unroll
            for (int c = 0; c < CC; ++c) p[2 + c] = fmaf(Wvert[c * HH + k], av, p[2 + c]);
        }
        if (idx >= 0) { Alist[idx * BB + b] = p[0]; Elist[idx * BB + b] = p[1]; }
        if (idx <= SS - 2) {
            float lv[CC]; float mx = -1e30f;
#pragma unroll
            for (int c = 0; c < CC; ++c) { lv[c] = p[2 + c] + bvert[c]; mx = fmaxf(mx, lv[c]); }
            float ev[CC]; float sum = 0.f;
#pragma unroll
            for (int c = 0; c < CC; ++c) { ev[c] = expf(lv[c] - mx); sum += ev[c]; }
            float inv = 1.f / sum;
#pragma unroll
            for (int c = 0; c < CC; ++c)
                out[OFF_ENC + (b * SS + (idx + 1)) * CC + c] = ev[c] * inv;
        }
        if (idx >= 1) {
            float be = bedge[0];
            float aprev = Alist[(idx - 1) * BB + b], eprev = Elist[(idx - 1) * BB + b];
            out[b * SS * SS + idx * SS + (idx - 1)] = (aprev + eprev + be >= 0.f) ? 1.f : 0.f;
            float acur = p[0];
            for (int vj = 0; vj <= idx - 2; ++vj)
                out[b * SS * SS + idx * SS + vj] =
                    (acur + Elist[vj * BB + b] + be >= 0.f) ? 1.f : 0.f;
        }
    }
}

extern "C" void kernel_launch(void* const* d_in, const int* in_sizes, int n_in,
                              void* d_out, int out_size, void* d_ws, size_t ws_size,
                              hipStream_t stream)
{
    const float* z     = (const float*)d_in[0];
    const float* dep   = (const float*)d_in[1];
    const float* xenc  = (const float*)d_in[2];
    const float* Wlin1 = (const float*)d_in[3];
    const float* blin1 = (const float*)d_in[4];
    const float* Wvert = (const float*)d_in[5];
    const float* bvert = (const float*)d_in[6];
    const float* Wedge = (const float*)d_in[7];
    const float* bedge = (const float*)d_in[8];
    const float* Wgate = (const float*)d_in[9];
    const float* bgate = (const float*)d_in[10];
    const float* Wmap  = (const float*)d_in[11];
    const float* bmap  = (const float*)d_in[12];
    const float* Wih   = (const float*)d_in[13];
    const float* bih   = (const float*)d_in[14];
    const float* Whh   = (const float*)d_in[15];
    const float* bhh   = (const float*)d_in[16];
    float* out = (float*)d_out;

    float* ws = (float*)d_ws;
    float* bufA  = ws;                    // zT, then hT      (H*B floats)
    float* bufB  = ws + HH * BB;          // g0T, then hinT   (H*B floats)
    float* Alist = ws + 2 * HH * BB;      // 16*B
    float* Elist = Alist + SS * BB;       // 16*B
    int*   cls   = (int*)(Elist + SS * BB);  // 16*B ints

    // dep-graph output rows: only cols < idx written; rest must be 0
    hipMemsetAsync(d_out, 0, (size_t)OFF_ENC * sizeof(float), stream);

    k_prep<<<288, 256, 0, stream>>>(z, xenc, bufA, cls);
    k_g0<<<256, 256, 0, stream>>>(bufA, Wlin1, blin1, bufB);
    // enc row 0 from g0 (dots only)
    k_post2<<<2, 256, 0, stream>>>(bufB, Wgate, bgate, Wmap, bmap, dep,
                                   Wedge, bedge, Wvert, bvert, -1, 0,
                                   bufB, Alist, Elist, out);
    for (int idx = 0; idx < SS; ++idx) {
        k_gru2<<<256, 256, 0, stream>>>(bufB, Whh, bhh, Wih, bih, cls, idx, bufA);
        int ngemm = (idx < SS - 1) ? 256 : 0;
        k_post2<<<ngemm + 2, 256, 0, stream>>>(bufA, Wgate, bgate, Wmap, bmap, dep,
                                               Wedge, bedge, Wvert, bvert, idx, ngemm,
                                               bufB, Alist, Elist, out);
    }
}

// Round 3
// 2000.864 us; speedup vs baseline: 1.4688x; 1.4688x over previous
//
#include <hip/hip_runtime.h>
#include <hip/hip_cooperative_groups.h>
#include <math.h>

namespace cg = cooperative_groups;

#define BB 512
#define SS 16
#define HH 501
#define KP 504               // K padded to multiple of 4 (pad weights = 0)
#define CC 7
#define OFF_ENC (BB*SS*SS)

struct SMemG {               // blocks 0..251 (GEMM role)
    float whh[12][KP];       // [gate*4+rl][k]
    float wlin[4][KP];
    float wpost[8][KP];      // [type*4+rl][k]  type0=gate, type1=map
};
struct SMemD {               // blocks 252..253 (dot role)
    float wdot[9][KP];       // rows: Wedge0, Wedge1, Wvert0..6
    float elds[SS][256];     // e(h_idx) history per local b
};
union SMem { SMemG g; SMemD d; };

__device__ __forceinline__ void dot9(const float* __restrict__ ap,
                                     const float (*__restrict__ wd)[KP],
                                     float* __restrict__ p)
{
#pragma unroll
    for (int j = 0; j < 9; ++j) p[j] = 0.f;
#pragma unroll 2
    for (int k = 0; k < KP; k += 4) {
        float4 w[9];
#pragma unroll
        for (int j = 0; j < 9; ++j) w[j] = *(const float4*)&wd[j][k];
        float a[4];
#pragma unroll
        for (int s = 0; s < 4; ++s) a[s] = ap[(k + s) * BB];
#pragma unroll
        for (int j = 0; j < 9; ++j) {
            p[j] = fmaf(w[j].x, a[0], p[j]);
            p[j] = fmaf(w[j].y, a[1], p[j]);
            p[j] = fmaf(w[j].z, a[2], p[j]);
            p[j] = fmaf(w[j].w, a[3], p[j]);
        }
    }
}

__global__ __launch_bounds__(256, 1) void k_all(
    const float* __restrict__ z,     const float* __restrict__ dep,
    const float* __restrict__ xenc,
    const float* __restrict__ Wlin1, const float* __restrict__ blin1,
    const float* __restrict__ Wvert, const float* __restrict__ bvert,
    const float* __restrict__ Wedge, const float* __restrict__ bedge,
    const float* __restrict__ Wgate, const float* __restrict__ bgate,
    const float* __restrict__ Wmap,  const float* __restrict__ bmap,
    const float* __restrict__ Wih,   const float* __restrict__ bih,
    const float* __restrict__ Whh,   const float* __restrict__ bhh,
    float* __restrict__ out,
    float* __restrict__ actIn,       // hin^T / g0^T  [KP][BB]
    float* __restrict__ actH,        // zT first, then h^T [KP][BB]
    int* __restrict__ cls)
{
    cg::grid_group grid = cg::this_grid();
    __shared__ SMem sm;
    __shared__ float ttile[32][33];

    const int bidx = blockIdx.x;
    const int tid  = threadIdx.x;
    const int lane = tid & 63;
    const int wv   = __builtin_amdgcn_readfirstlane(tid >> 6);

    // role constants (GEMM role, bidx<252)
    const int g   = bidx >> 1;          // row group 0..125
    const int bg  = bidx & 1;           // b half
    const int rh  = wv >> 1;            // row pair within group
    const int bh  = wv & 1;             // b quarter
    const int rl0 = rh * 2;             // local row 0..3 base
    const int r0  = g * 4 + rl0;        // global out-row base
    const int bcol = bg * 256 + bh * 128 + lane * 2;

    // ---------------- P0: transpose z -> actH, load weights, cls, zero dep ----
    {
        const int bt = bidx >> 4, kt = bidx & 15;
        const int b0 = bt * 32, k0 = kt * 32;
        const int tx = tid & 31, ty = tid >> 5;
#pragma unroll
        for (int i = 0; i < 4; ++i) {
            int row = ty + i * 8;
            if (k0 + tx < HH) ttile[row][tx] = z[(b0 + row) * HH + k0 + tx];
        }
        __syncthreads();
#pragma unroll
        for (int i = 0; i < 4; ++i) {
            int row = ty + i * 8;
            if (k0 + row < HH) actH[(k0 + row) * BB + b0 + tx] = ttile[tx][row];
        }
    }
    if (bidx < 252) {
#pragma unroll
        for (int j = 0; j < 12; ++j) {
            int gate = j >> 2, rl = j & 3;
            int R = gate * HH + min(g * 4 + rl, HH - 1);
            for (int kk = tid; kk < KP; kk += 256)
                sm.g.whh[j][kk] = (kk < HH) ? Whh[R * HH + kk] : 0.f;
        }
#pragma unroll
        for (int j = 0; j < 4; ++j) {
            int R = min(g * 4 + j, HH - 1);
            for (int kk = tid; kk < KP; kk += 256)
                sm.g.wlin[j][kk] = (kk < HH) ? Wlin1[R * HH + kk] : 0.f;
        }
#pragma unroll
        for (int j = 0; j < 8; ++j) {
            int type = j >> 2, rl = j & 3;
            int R = min(g * 4 + rl, HH - 1);
            const float* W = type ? Wmap : Wgate;
            for (int kk = tid; kk < KP; kk += 256)
                sm.g.wpost[j][kk] = (kk < HH) ? W[R * HH + kk] : 0.f;
        }
    } else {
        if (bidx < 254) {
#pragma unroll
            for (int j = 0; j < 9; ++j) {
                const float* W = (j < 2) ? (Wedge + j * HH) : (Wvert + (j - 2) * HH);
                for (int kk = tid; kk < KP; kk += 256)
                    sm.d.wdot[j][kk] = (kk < HH) ? W[kk] : 0.f;
            }
        }
        // cls extraction: 4 blocks x 256 threads x 8 entries
        int base = (bidx - 252) * 2048 + tid * 8;
#pragma unroll
        for (int q = 0; q < 8; ++q) {
            int e = base + q; int s = e >> 9, b = e & 511;
            const float* xp = xenc + (b * SS + s) * CC;
            int c = 0;
#pragma unroll
            for (int cc = 0; cc < CC; ++cc) if (xp[cc] > 0.5f) c = cc;
            cls[s * BB + b] = c;
        }
        // zero dep-graph output region (131072 floats = 32768 float4)
        float4 z4 = make_float4(0.f, 0.f, 0.f, 0.f);
#pragma unroll
        for (int q = 0; q < 32; ++q)
            ((float4*)out)[(bidx - 252) * 8192 + q * 256 + tid] = z4;
    }
    grid.sync();

    // ---------------- G0: actIn = (z @ Wlin1^T + b)^T  (reads actH = zT) -----
    if (bidx < 252) {
        float acc[4] = {};
        const float* ap = actH + bcol;
#pragma unroll 2
        for (int k = 0; k < KP; k += 4) {
            float4 w[2];
#pragma unroll
            for (int j = 0; j < 2; ++j) w[j] = *(const float4*)&sm.g.wlin[rl0 + j][k];
            float2 a[4];
#pragma unroll
            for (int s = 0; s < 4; ++s) a[s] = *(const float2*)(ap + (k + s) * BB);
#pragma unroll
            for (int j = 0; j < 2; ++j) {
                float wc[4] = {w[j].x, w[j].y, w[j].z, w[j].w};
#pragma unroll
                for (int s = 0; s < 4; ++s) {
                    acc[j * 2 + 0] = fmaf(wc[s], a[s].x, acc[j * 2 + 0]);
                    acc[j * 2 + 1] = fmaf(wc[s], a[s].y, acc[j * 2 + 1]);
                }
            }
        }
#pragma unroll
        for (int rr = 0; rr < 2; ++rr) {
            int r = r0 + rr;
            if (r < HH) {
                actIn[r * BB + bcol + 0] = acc[rr * 2 + 0] + blin1[r];
                actIn[r * BB + bcol + 1] = acc[rr * 2 + 1] + blin1[r];
            }
        }
    }
    grid.sync();

    float a_prev = 0.f;   // dot-role per-thread state: a(h_{idx-1})

    for (int idx = 0; idx < SS; ++idx) {
        // ---------- phase A: GRU (actIn -> actH); dots0 for enc row 0 ----------
        if (bidx < 252) {
            float acc[12] = {};
            const float* ap = actIn + bcol;
#pragma unroll 2
            for (int k = 0; k < KP; k += 4) {
                float4 w[6];
#pragma unroll
                for (int j = 0; j < 6; ++j)
                    w[j] = *(const float4*)&sm.g.whh[(j >> 1) * 4 + rl0 + (j & 1)][k];
                float2 a[4];
#pragma unroll
                for (int s = 0; s < 4; ++s) a[s] = *(const float2*)(ap + (k + s) * BB);
#pragma unroll
                for (int j = 0; j < 6; ++j) {
                    float wc[4] = {w[j].x, w[j].y, w[j].z, w[j].w};
#pragma unroll
                    for (int s = 0; s < 4; ++s) {
                        acc[j * 2 + 0] = fmaf(wc[s], a[s].x, acc[j * 2 + 0]);
                        acc[j * 2 + 1] = fmaf(wc[s], a[s].y, acc[j * 2 + 1]);
                    }
                }
            }
            int c_[2] = { cls[idx * BB + bcol], cls[idx * BB + bcol + 1] };
#pragma unroll
            for (int rr = 0; rr < 2; ++rr) {
                int r = r0 + rr;
                if (r < HH) {
                    float bh0 = bhh[r], bh1 = bhh[HH + r], bh2 = bhh[2 * HH + r];
                    float bi0 = bih[r], bi1 = bih[HH + r], bi2 = bih[2 * HH + r];
#pragma unroll
                    for (int bb = 0; bb < 2; ++bb) {
                        int c = c_[bb];
                        float gi0 = Wih[r * CC + c] + bi0;
                        float gi1 = Wih[(HH + r) * CC + c] + bi1;
                        float gi2 = Wih[(2 * HH + r) * CC + c] + bi2;
                        float gh0 = acc[0 + rr * 2 + bb] + bh0;
                        float gh1 = acc[4 + rr * 2 + bb] + bh1;
                        float gh2 = acc[8 + rr * 2 + bb] + bh2;
                        float rg = 1.f / (1.f + expf(-(gi0 + gh0)));
                        float ug = 1.f / (1.f + expf(-(gi1 + gh1)));
                        float ng = tanhf(gi2 + rg * gh2);
                        float hprev = actIn[r * BB + bcol + bb];
                        actH[r * BB + bcol + bb] = (1.f - ug) * ng + ug * hprev;
                    }
                }
            }
        } else if (bidx < 254 && idx == 0) {
            // enc row 0 from g0 (actIn)
            const int db = (bidx - 252) * 256 + tid;
            float p[9];
            dot9(actIn + db, sm.d.wdot, p);
            float lv[CC]; float mx = -1e30f;
#pragma unroll
            for (int c = 0; c < CC; ++c) { lv[c] = p[2 + c] + bvert[c]; mx = fmaxf(mx, lv[c]); }
            float sum = 0.f; float ev[CC];
#pragma unroll
            for (int c = 0; c < CC; ++c) { ev[c] = expf(lv[c] - mx); sum += ev[c]; }
            float inv = 1.f / sum;
#pragma unroll
            for (int c = 0; c < CC; ++c)
                out[OFF_ENC + (db * SS + 0) * CC + c] = ev[c] * inv;
        }
        grid.sync();

        // ---------- phase B: post (actH -> actIn) + dots/outputs on actH -------
        if (bidx < 252) {
            if (idx < SS - 1) {
                float acc[8] = {};
                const float* ap = actH + bcol;
#pragma unroll 2
                for (int k = 0; k < KP; k += 4) {
                    float4 w[4];
#pragma unroll
                    for (int j = 0; j < 4; ++j)
                        w[j] = *(const float4*)&sm.g.wpost[(j >> 1) * 4 + rl0 + (j & 1)][k];
                    float2 a[4];
#pragma unroll
                    for (int s = 0; s < 4; ++s) a[s] = *(const float2*)(ap + (k + s) * BB);
#pragma unroll
                    for (int j = 0; j < 4; ++j) {
                        float wc[4] = {w[j].x, w[j].y, w[j].z, w[j].w};
#pragma unroll
                        for (int s = 0; s < 4; ++s) {
                            acc[j * 2 + 0] = fmaf(wc[s], a[s].x, acc[j * 2 + 0]);
                            acc[j * 2 + 1] = fmaf(wc[s], a[s].y, acc[j * 2 + 1]);
                        }
                    }
                }
#pragma unroll
                for (int rr = 0; rr < 2; ++rr) {
                    int r = r0 + rr;
                    if (r < HH) {
                        float bgv = bgate[r], bmv = bmap[r];
                        float c0 = (1.f / (1.f + expf(-bgv))) * bmv;
#pragma unroll
                        for (int bb = 0; bb < 2; ++bb) {
                            float yg = acc[rr * 2 + bb] + bgv;
                            float ym = acc[4 + rr * 2 + bb] + bmv;
                            float f  = (1.f / (1.f + expf(-yg))) * ym;
                            float d  = dep[(bcol + bb) * (SS * SS) + (idx + 1) * SS + idx];
                            actIn[r * BB + bcol + bb] = (d != 0.f) ? (f + 15.f * c0)
                                                                   : (16.f * c0);
                        }
                    }
                }
            }
        } else if (bidx < 254) {
            const int db = (bidx - 252) * 256 + tid;
            float p[9];
            dot9(actH + db, sm.d.wdot, p);
            sm.d.elds[idx][tid] = p[1];
            if (idx <= SS - 2) {
                float lv[CC]; float mx = -1e30f;
#pragma unroll
                for (int c = 0; c < CC; ++c) { lv[c] = p[2 + c] + bvert[c]; mx = fmaxf(mx, lv[c]); }
                float sum = 0.f; float ev[CC];
#pragma unroll
                for (int c = 0; c < CC; ++c) { ev[c] = expf(lv[c] - mx); sum += ev[c]; }
                float inv = 1.f / sum;
#pragma unroll
                for (int c = 0; c < CC; ++c)
                    out[OFF_ENC + (db * SS + (idx + 1)) * CC + c] = ev[c] * inv;
            }
            if (idx >= 1) {
                float be = bedge[0];
                float eprev = sm.d.elds[idx - 1][tid];
                out[db * SS * SS + idx * SS + (idx - 1)] =
                    (a_prev + eprev + be >= 0.f) ? 1.f : 0.f;
                for (int vj = 0; vj <= idx - 2; ++vj)
                    out[db * SS * SS + idx * SS + vj] =
                        (p[0] + sm.d.elds[vj][tid] + be >= 0.f) ? 1.f : 0.f;
            }
            a_prev = p[0];
        }
        if (idx < SS - 1) grid.sync();
    }
}

extern "C" void kernel_launch(void* const* d_in, const int* in_sizes, int n_in,
                              void* d_out, int out_size, void* d_ws, size_t ws_size,
                              hipStream_t stream)
{
    const float* z     = (const float*)d_in[0];
    const float* dep   = (const float*)d_in[1];
    const float* xenc  = (const float*)d_in[2];
    const float* Wlin1 = (const float*)d_in[3];
    const float* blin1 = (const float*)d_in[4];
    const float* Wvert = (const float*)d_in[5];
    const float* bvert = (const float*)d_in[6];
    const float* Wedge = (const float*)d_in[7];
    const float* bedge = (const float*)d_in[8];
    const float* Wgate = (const float*)d_in[9];
    const float* bgate = (const float*)d_in[10];
    const float* Wmap  = (const float*)d_in[11];
    const float* bmap  = (const float*)d_in[12];
    const float* Wih   = (const float*)d_in[13];
    const float* bih   = (const float*)d_in[14];
    const float* Whh   = (const float*)d_in[15];
    const float* bhh   = (const float*)d_in[16];
    float* out = (float*)d_out;

    float* ws    = (float*)d_ws;
    float* actIn = ws;                       // KP*BB
    float* actH  = ws + KP * BB;             // KP*BB
    int*   cls   = (int*)(ws + 2 * KP * BB); // SS*BB ints

    void* args[] = {
        (void*)&z, (void*)&dep, (void*)&xenc,
        (void*)&Wlin1, (void*)&blin1, (void*)&Wvert, (void*)&bvert,
        (void*)&Wedge, (void*)&bedge, (void*)&Wgate, (void*)&bgate,
        (void*)&Wmap, (void*)&bmap, (void*)&Wih, (void*)&bih,
        (void*)&Whh, (void*)&bhh,
        (void*)&out, (void*)&actIn, (void*)&actH, (void*)&cls
    };
    hipLaunchCooperativeKernel((const void*)k_all, dim3(256), dim3(256),
                               args, 0, stream);
}

// Round 4
// 1523.291 us; speedup vs baseline: 1.9292x; 1.3135x over previous
//
#include <hip/hip_runtime.h>
#include <math.h>

#define BB 512
#define SS 16
#define HH 501
#define KP 504
#define CC 7
#define OFF_ENC (BB*SS*SS)

// ws layout (float offsets)
#define O_BUFIN 0
#define O_BUFH  (KP*BB)
#define O_WHH   (2*KP*BB)                 // [3*KP][KP] padded Whh
#define O_WPOST (O_WHH + 3*KP*KP)         // [2*KP][KP] padded Wgate,Wmap
#define O_WLIN  (O_WPOST + 2*KP*KP)       // [KP][KP]  padded Wlin1
#define O_WDOT  (O_WLIN + KP*KP)          // [9][KP]   Wedge(2) + Wvert(7)
#define O_ALIST (O_WDOT + 9*KP)           // SS*BB
#define O_ELIST (O_ALIST + SS*BB)         // SS*BB
#define O_CLS   (O_ELIST + SS*BB)         // SS*BB ints

// ---------------- prep: transpose z, pad weights, cls, zero out regions -----
__global__ __launch_bounds__(256) void k_prep(
    const float* __restrict__ z, const float* __restrict__ xenc,
    const float* __restrict__ Wlin1, const float* __restrict__ Wgate,
    const float* __restrict__ Wmap,  const float* __restrict__ Whh,
    const float* __restrict__ Wedge, const float* __restrict__ Wvert,
    float* __restrict__ ws, float* __restrict__ out)
{
    const int b = blockIdx.x, tid = threadIdx.x;
    float* bufIn = ws + O_BUFIN;
    float* bufH  = ws + O_BUFH;
    if (b < 256) {
        // transpose z[512][501] -> bufH[KP][512]
        __shared__ float t[32][33];
        const int bt = b >> 4, kt = b & 15;
        const int b0 = bt * 32, k0 = kt * 32;
        const int tx = tid & 31, ty = tid >> 5;
#pragma unroll
        for (int i = 0; i < 4; ++i) {
            int row = ty + i * 8;
            if (k0 + tx < HH) t[row][tx] = z[(b0 + row) * HH + k0 + tx];
        }
        __syncthreads();
#pragma unroll
        for (int i = 0; i < 4; ++i) {
            int row = ty + i * 8;
            if (k0 + row < HH) bufH[(k0 + row) * BB + b0 + tx] = t[tx][row];
        }
    } else if (b == 256) {
        // zero pad rows HH..KP-1 of both act buffers
        for (int q = tid; q < (KP - HH) * BB; q += 256) {
            bufH[HH * BB + q] = 0.f;
            bufIn[HH * BB + q] = 0.f;
        }
    } else if (b < 265) {
        // cls extraction: 8 blocks x 256 threads x 4
        int* cls = (int*)(ws + O_CLS);
        int base = (b - 257) * 1024 + tid * 4;
#pragma unroll
        for (int q = 0; q < 4; ++q) {
            int e = base + q; int s = e >> 9, bb = e & 511;
            const float* xp = xenc + (bb * SS + s) * CC;
            int c = 0;
#pragma unroll
            for (int cc = 0; cc < CC; ++cc) if (xp[cc] > 0.5f) c = cc;
            cls[s * BB + bb] = c;
        }
    } else if (b < 297) {
        // zero dep-graph output region: 32 blocks x 1024 float4
        float4 z4 = make_float4(0.f, 0.f, 0.f, 0.f);
        float4* o4 = (float4*)out;
#pragma unroll
        for (int q = 0; q < 4; ++q)
            o4[(b - 265) * 1024 + q * 256 + tid] = z4;
    } else if (b < 423) {
        // padded weight copies: 126 blocks x 24 rows
        int j0 = (b - 297) * 24;
        for (int jj = 0; jj < 24; ++jj) {
            int j = j0 + jj;
            const float* src; float* dst; int r;
            if (j < 3 * KP) {
                int gate = j / KP; r = j % KP;
                src = Whh + (gate * HH + min(r, HH - 1)) * HH;
                dst = ws + O_WHH + j * KP;
            } else if (j < 5 * KP) {
                int j2 = j - 3 * KP; int t2 = j2 / KP; r = j2 % KP;
                src = (t2 ? Wmap : Wgate) + min(r, HH - 1) * HH;
                dst = ws + O_WPOST + j2 * KP;
            } else {
                r = j - 5 * KP;
                src = Wlin1 + min(r, HH - 1) * HH;
                dst = ws + O_WLIN + r * KP;
            }
            bool zr = (r >= HH);
            for (int kk = tid; kk < KP; kk += 256)
                dst[kk] = (!zr && kk < HH) ? src[kk] : 0.f;
        }
    } else {
        // WdotP: 9 rows
        for (int j = 0; j < 9; ++j) {
            const float* src = (j < 2) ? (Wedge + j * HH) : (Wvert + (j - 2) * HH);
            for (int kk = tid; kk < KP; kk += 256)
                ws[O_WDOT + j * KP + kk] = (kk < HH) ? src[kk] : 0.f;
        }
    }
}

// ---------------- g0 = (z @ Wlin1^T + b)^T : bufH(zT) -> bufIn --------------
__global__ __launch_bounds__(256) void k_g0(
    const float* __restrict__ act, const float* __restrict__ W,
    const float* __restrict__ blin1, float* __restrict__ dst)
{
    const int g = blockIdx.x >> 1, ch = blockIdx.x & 1;
    const int r0 = g * 4;
    const int col = ch * 256 + threadIdx.x;
    const float* wp[4];
#pragma unroll
    for (int i = 0; i < 4; ++i) wp[i] = W + (r0 + i) * KP;
    float acc[4] = {};
    const float* ap = act + col;
    for (int k = 0; k < KP; k += 8) {
        float a[8];
#pragma unroll
        for (int s = 0; s < 8; ++s) a[s] = ap[(k + s) * BB];
#pragma unroll
        for (int i = 0; i < 4; ++i) {
            float4 w0 = *(const float4*)(wp[i] + k);
            float4 w1 = *(const float4*)(wp[i] + k + 4);
            acc[i] = fmaf(w0.x, a[0], acc[i]); acc[i] = fmaf(w0.y, a[1], acc[i]);
            acc[i] = fmaf(w0.z, a[2], acc[i]); acc[i] = fmaf(w0.w, a[3], acc[i]);
            acc[i] = fmaf(w1.x, a[4], acc[i]); acc[i] = fmaf(w1.y, a[5], acc[i]);
            acc[i] = fmaf(w1.z, a[6], acc[i]); acc[i] = fmaf(w1.w, a[7], acc[i]);
        }
    }
#pragma unroll
    for (int i = 0; i < 4; ++i) {
        int r = r0 + i;
        if (r < HH) dst[r * BB + col] = acc[i] + blin1[r];
    }
}

// ---------------- GRU: bufIn(hin) -> bufH(h) --------------------------------
__global__ __launch_bounds__(256) void k_gru(
    const float* __restrict__ act, const float* __restrict__ W,
    const int* __restrict__ cls,
    const float* __restrict__ bhh, const float* __restrict__ Wih,
    const float* __restrict__ bih, int idx,
    float* __restrict__ dst)
{
    const int g = blockIdx.x >> 1, ch = blockIdx.x & 1;
    const int r0 = g * 2;
    const int col = ch * 256 + threadIdx.x;
    const float* wp[6];
#pragma unroll
    for (int gg = 0; gg < 3; ++gg)
#pragma unroll
        for (int rr = 0; rr < 2; ++rr)
            wp[gg * 2 + rr] = W + (gg * KP + r0 + rr) * KP;
    float acc[6] = {};
    const float* ap = act + col;
    for (int k = 0; k < KP; k += 8) {
        float a[8];
#pragma unroll
        for (int s = 0; s < 8; ++s) a[s] = ap[(k + s) * BB];
#pragma unroll
        for (int j = 0; j < 6; ++j) {
            float4 w0 = *(const float4*)(wp[j] + k);
            float4 w1 = *(const float4*)(wp[j] + k + 4);
            acc[j] = fmaf(w0.x, a[0], acc[j]); acc[j] = fmaf(w0.y, a[1], acc[j]);
            acc[j] = fmaf(w0.z, a[2], acc[j]); acc[j] = fmaf(w0.w, a[3], acc[j]);
            acc[j] = fmaf(w1.x, a[4], acc[j]); acc[j] = fmaf(w1.y, a[5], acc[j]);
            acc[j] = fmaf(w1.z, a[6], acc[j]); acc[j] = fmaf(w1.w, a[7], acc[j]);
        }
    }
    const int c = cls[idx * BB + col];
#pragma unroll
    for (int rr = 0; rr < 2; ++rr) {
        int r = r0 + rr;
        if (r < HH) {
            float gh0 = acc[0 + rr] + bhh[r];
            float gh1 = acc[2 + rr] + bhh[HH + r];
            float gh2 = acc[4 + rr] + bhh[2 * HH + r];
            float gi0 = Wih[r * CC + c] + bih[r];
            float gi1 = Wih[(HH + r) * CC + c] + bih[HH + r];
            float gi2 = Wih[(2 * HH + r) * CC + c] + bih[2 * HH + r];
            float rg = 1.f / (1.f + expf(-(gi0 + gh0)));
            float ug = 1.f / (1.f + expf(-(gi1 + gh1)));
            float ng = tanhf(gi2 + rg * gh2);
            float hprev = act[r * BB + col];
            dst[r * BB + col] = (1.f - ug) * ng + ug * hprev;
        }
    }
}

// ---------------- post: bufH(h) -> bufIn(hin next) + dots/outputs -----------
__global__ __launch_bounds__(256) void k_post(
    const float* __restrict__ actH, const float* __restrict__ actIn,
    const float* __restrict__ Wp, const float* __restrict__ Wd,
    const float* __restrict__ bgate, const float* __restrict__ bmap,
    const float* __restrict__ dep,
    const float* __restrict__ bedge, const float* __restrict__ bvert,
    int idx, int ngemm, int dsrc,
    float* __restrict__ dst, float* __restrict__ Alist,
    float* __restrict__ Elist, float* __restrict__ out)
{
    const int tid = threadIdx.x;
    if ((int)blockIdx.x < ngemm) {
        const int g = blockIdx.x >> 1, ch = blockIdx.x & 1;
        const int r0 = g * 2;
        const int col = ch * 256 + tid;
        const float* wp[4];
#pragma unroll
        for (int t2 = 0; t2 < 2; ++t2)
#pragma unroll
            for (int rr = 0; rr < 2; ++rr)
                wp[t2 * 2 + rr] = Wp + (t2 * KP + r0 + rr) * KP;
        float acc[4] = {};
        const float* ap = actH + col;
        for (int k = 0; k < KP; k += 8) {
            float a[8];
#pragma unroll
            for (int s = 0; s < 8; ++s) a[s] = ap[(k + s) * BB];
#pragma unroll
            for (int j = 0; j < 4; ++j) {
                float4 w0 = *(const float4*)(wp[j] + k);
                float4 w1 = *(const float4*)(wp[j] + k + 4);
                acc[j] = fmaf(w0.x, a[0], acc[j]); acc[j] = fmaf(w0.y, a[1], acc[j]);
                acc[j] = fmaf(w0.z, a[2], acc[j]); acc[j] = fmaf(w0.w, a[3], acc[j]);
                acc[j] = fmaf(w1.x, a[4], acc[j]); acc[j] = fmaf(w1.y, a[5], acc[j]);
                acc[j] = fmaf(w1.z, a[6], acc[j]); acc[j] = fmaf(w1.w, a[7], acc[j]);
            }
        }
        const float d = dep[col * (SS * SS) + (idx + 1) * SS + idx];
#pragma unroll
        for (int rr = 0; rr < 2; ++rr) {
            int r = r0 + rr;
            if (r < HH) {
                float bgv = bgate[r], bmv = bmap[r];
                float yg = acc[0 + rr] + bgv;
                float ym = acc[2 + rr] + bmv;
                float f  = (1.f / (1.f + expf(-yg))) * ym;
                float c0 = (1.f / (1.f + expf(-bgv))) * bmv;
                dst[r * BB + col] = (d != 0.f) ? (f + 15.f * c0) : (16.f * c0);
            }
        }
    } else {
        const int db = ((int)blockIdx.x - ngemm) * 256 + tid;
        const float* hp = (dsrc ? actH : actIn) + db;
        float p[9];
#pragma unroll
        for (int j = 0; j < 9; ++j) p[j] = 0.f;
        for (int k = 0; k < KP; k += 4) {
            float4 w[9];
#pragma unroll
            for (int j = 0; j < 9; ++j) w[j] = *(const float4*)(Wd + j * KP + k);
            float a[4];
#pragma unroll
            for (int s = 0; s < 4; ++s) a[s] = hp[(k + s) * BB];
#pragma unroll
            for (int j = 0; j < 9; ++j) {
                p[j] = fmaf(w[j].x, a[0], p[j]);
                p[j] = fmaf(w[j].y, a[1], p[j]);
                p[j] = fmaf(w[j].z, a[2], p[j]);
                p[j] = fmaf(w[j].w, a[3], p[j]);
            }
        }
        if (idx >= 0) { Alist[idx * BB + db] = p[0]; Elist[idx * BB + db] = p[1]; }
        if (idx <= SS - 2) {
            float lv[CC]; float mx = -1e30f;
#pragma unroll
            for (int c = 0; c < CC; ++c) { lv[c] = p[2 + c] + bvert[c]; mx = fmaxf(mx, lv[c]); }
            float sum = 0.f; float ev[CC];
#pragma unroll
            for (int c = 0; c < CC; ++c) { ev[c] = expf(lv[c] - mx); sum += ev[c]; }
            float inv = 1.f / sum;
#pragma unroll
            for (int c = 0; c < CC; ++c)
                out[OFF_ENC + (db * SS + (idx + 1)) * CC + c] = ev[c] * inv;
        }
        if (idx >= 1) {
            float be = bedge[0];
            float aprev = Alist[(idx - 1) * BB + db], eprev = Elist[(idx - 1) * BB + db];
            out[db * SS * SS + idx * SS + (idx - 1)] =
                (aprev + eprev + be >= 0.f) ? 1.f : 0.f;
            for (int vj = 0; vj <= idx - 2; ++vj)
                out[db * SS * SS + idx * SS + vj] =
                    (p[0] + Elist[vj * BB + db] + be >= 0.f) ? 1.f : 0.f;
        }
    }
}

extern "C" void kernel_launch(void* const* d_in, const int* in_sizes, int n_in,
                              void* d_out, int out_size, void* d_ws, size_t ws_size,
                              hipStream_t stream)
{
    const float* z     = (const float*)d_in[0];
    const float* dep   = (const float*)d_in[1];
    const float* xenc  = (const float*)d_in[2];
    const float* Wlin1 = (const float*)d_in[3];
    const float* blin1 = (const float*)d_in[4];
    const float* Wvert = (const float*)d_in[5];
    const float* bvert = (const float*)d_in[6];
    const float* Wedge = (const float*)d_in[7];
    const float* bedge = (const float*)d_in[8];
    const float* Wgate = (const float*)d_in[9];
    const float* bgate = (const float*)d_in[10];
    const float* Wmap  = (const float*)d_in[11];
    const float* bmap  = (const float*)d_in[12];
    const float* Wih   = (const float*)d_in[13];
    const float* bih   = (const float*)d_in[14];
    const float* Whh   = (const float*)d_in[15];
    const float* bhh   = (const float*)d_in[16];
    float* out = (float*)d_out;

    float* ws    = (float*)d_ws;
    float* bufIn = ws + O_BUFIN;
    float* bufH  = ws + O_BUFH;
    float* WhhP  = ws + O_WHH;
    float* WpostP= ws + O_WPOST;
    float* WlinP = ws + O_WLIN;
    float* WdotP = ws + O_WDOT;
    float* Alist = ws + O_ALIST;
    float* Elist = ws + O_ELIST;
    int*   cls   = (int*)(ws + O_CLS);

    k_prep<<<424, 256, 0, stream>>>(z, xenc, Wlin1, Wgate, Wmap, Whh,
                                    Wedge, Wvert, ws, out);
    k_g0<<<252, 256, 0, stream>>>(bufH, WlinP, blin1, bufIn);
    // enc row 0 from g0 (dots only, src = bufIn)
    k_post<<<2, 256, 0, stream>>>(bufH, bufIn, WpostP, WdotP, bgate, bmap, dep,
                                  bedge, bvert, -1, 0, 0,
                                  bufIn, Alist, Elist, out);
    for (int idx = 0; idx < SS; ++idx) {
        k_gru<<<502, 256, 0, stream>>>(bufIn, WhhP, cls, bhh, Wih, bih, idx, bufH);
        int ng = (idx < SS - 1) ? 502 : 0;
        k_post<<<ng + 2, 256, 0, stream>>>(bufH, bufIn, WpostP, WdotP, bgate, bmap,
                                           dep, bedge, bvert, idx, ng, 1,
                                           bufIn, Alist, Elist, out);
    }
}